// Round 4
// baseline (3135.440 us; speedup 1.0000x reference)
//
#include <hip/hip_runtime.h>

// Fused RNN scan: h_{t+1} = tanh(W_ih x_t + b_ih + b_hh + W_hh h_t)
// R3b: 16 blocks x 256 threads (4 waves, j-tile 32 each = 2 MFMA subtiles).
// LDS holds ONLY h (double-buffered, XOR-swizzled): per step 16 ds_read_b128
// + 8 ds_write_b64 total (was 48 reads with 8 waves) -- LDS pipe was the
// dominant per-step cost. x comes via per-lane global loads into a depth-3
// register ring (redundant across waves, L1-resident, off critical path);
// ih-projection MFMAs for step t+1 issue late in body t, off the h chain.
// (R3 fix: cvt_pkrtz returns __fp16x2 -> bit_cast into _Float16 vectors.)

#define SEQ   4096
#define BATCH 256
#define DIN   64
#define DH    128
#define XSTEP (BATCH * DIN)

typedef _Float16 half8  __attribute__((ext_vector_type(8)));
typedef _Float16 half4v __attribute__((ext_vector_type(4)));
typedef _Float16 half2v __attribute__((ext_vector_type(2)));
typedef __fp16   fp16x2 __attribute__((ext_vector_type(2)));
typedef float    f32x4  __attribute__((ext_vector_type(4)));

union H2 { fp16x2 q; half2v h; unsigned int u; };

// tanh(x) = 1 - 2/(1 + e^{2x}); overflow-free for all finite x.
__device__ __forceinline__ float fast_tanh(float v) {
    float e = __builtin_amdgcn_exp2f(v * 2.88539008177792681472f);
    return 1.0f - 2.0f * __builtin_amdgcn_rcpf(e + 1.0f);
}

// byte offset of h[b][j] (f16) in a [16][128] tile; 16B-chunk XOR swizzle by b.
__device__ __forceinline__ int hoff(int b, int j) {
    return b * 256 + ((((j >> 3) ^ b) & 15) << 4) + (j & 7) * 2;
}

__device__ __forceinline__ half2v pk(float a, float b) {
    H2 u; u.q = __builtin_amdgcn_cvt_pkrtz(a, b);
    return u.h;
}

__device__ __forceinline__ half8 cvt8(f32x4 a, f32x4 b) {
    half2v p0 = pk(a[0], a[1]);
    half2v p1 = pk(a[2], a[3]);
    half2v p2 = pk(b[0], b[1]);
    half2v p3 = pk(b[2], b[3]);
    half8 r;
    r[0] = p0[0]; r[1] = p0[1]; r[2] = p1[0]; r[3] = p1[1];
    r[4] = p2[0]; r[5] = p2[1]; r[6] = p3[0]; r[7] = p3[1];
    return r;
}

__device__ __forceinline__ half4v pack4(f32x4 a) {
    half2v q0 = pk(a[0], a[1]);
    half2v q1 = pk(a[2], a[3]);
    half4v r;
    r[0] = q0[0]; r[1] = q0[1]; r[2] = q1[0]; r[3] = q1[1];
    return r;
}

struct XSlot { f32x4 v0, v1, v2, v3; };   // 16 f32 = both k-frags of one step

__launch_bounds__(256, 1)
__global__ void rnn_fused_scan(const float* __restrict__ x,     // [SEQ][BATCH][DIN]
                               const float* __restrict__ Wih,   // [DH][DIN]
                               const float* __restrict__ bih,   // [DH]
                               const float* __restrict__ Whh,   // [DH][DH]
                               const float* __restrict__ bhh,   // [DH]
                               float* __restrict__ out)         // [BATCH][DH]
{
    __shared__ __align__(16) char hbuf[8192];   // 2 x swizzled [16][128] f16

    const int tid   = threadIdx.x;
    const int w     = tid >> 6;
    const int lane  = tid & 63;
    const int lb    = lane & 15;   // b-col (B/C/D) and m-row (A)
    const int lg    = lane >> 4;   // k-group (A/B), row-group (C/D)
    const int bbase = blockIdx.x << 4;
    const int jA    = (w << 5) + lb;   // A-frag rows, subtile A
    const int jB    = jA + 16;          // subtile B

    // ---- persistent weights as fp16 frags ----
    half8 AhhA[4], AhhB[4], AihA[2], AihB[2];
    #pragma unroll
    for (int kt = 0; kt < 4; ++kt) {
        const float* ra = Whh + jA * DH + kt * 32 + lg * 8;
        const float* rb = Whh + jB * DH + kt * 32 + lg * 8;
        half8 fa, fb;
        #pragma unroll
        for (int i = 0; i < 8; ++i) { fa[i] = (_Float16)ra[i]; fb[i] = (_Float16)rb[i]; }
        AhhA[kt] = fa; AhhB[kt] = fb;
    }
    #pragma unroll
    for (int kt = 0; kt < 2; ++kt) {
        const float* ra = Wih + jA * DIN + kt * 32 + lg * 8;
        const float* rb = Wih + jB * DIN + kt * 32 + lg * 8;
        half8 fa, fb;
        #pragma unroll
        for (int i = 0; i < 8; ++i) { fa[i] = (_Float16)ra[i]; fb[i] = (_Float16)rb[i]; }
        AihA[kt] = fa; AihB[kt] = fb;
    }
    f32x4 biasA, biasB;
    #pragma unroll
    for (int r = 0; r < 4; ++r) {
        int j = (w << 5) + lg * 4 + r;
        biasA[r] = bih[j] + bhh[j];
        biasB[r] = bih[j + 16] + bhh[j + 16];
    }

    // ---- x: per-lane pointer; 16 f32/step (both k-frags), depth-3 ring ----
    const float* xb = x + (size_t)(bbase + lb) * DIN + lg * 8;
    #define XLOAD(slot, p_) do {                                           \
        (slot).v0 = *(const f32x4*)(p_);                                   \
        (slot).v1 = *(const f32x4*)((p_) + 4);                             \
        (slot).v2 = *(const f32x4*)((p_) + 32);                            \
        (slot).v3 = *(const f32x4*)((p_) + 36);                            \
    } while (0)

    XSlot xr1, xr2, xr3, x0;
    XLOAD(x0, xb);
    XLOAD(xr1, xb + 1 * (size_t)XSTEP);
    XLOAD(xr2, xb + 2 * (size_t)XSTEP);
    XLOAD(xr3, xb + 3 * (size_t)XSTEP);
    const float* xload = xb + 4 * (size_t)XSTEP;   // -> x[min(t+4, SEQ-1)]

    // acc_ih for t=0
    f32x4 accA, accB;
    {
        half8 xf0 = cvt8(x0.v0, x0.v1);
        half8 xf1 = cvt8(x0.v2, x0.v3);
        accA = __builtin_amdgcn_mfma_f32_16x16x32_f16(AihA[0], xf0, biasA, 0, 0, 0);
        accA = __builtin_amdgcn_mfma_f32_16x16x32_f16(AihA[1], xf1, accA,  0, 0, 0);
        accB = __builtin_amdgcn_mfma_f32_16x16x32_f16(AihB[0], xf0, biasB, 0, 0, 0);
        accB = __builtin_amdgcn_mfma_f32_16x16x32_f16(AihB[1], xf1, accB,  0, 0, 0);
    }

    half8 hf0, hf1, hf2, hf3;
    {
        half8 z;
        #pragma unroll
        for (int i = 0; i < 8; ++i) z[i] = (_Float16)0.0f;
        hf0 = hf1 = hf2 = hf3 = z;   // h_0 = 0
    }

    // write offsets (bytes): subtile A at j=(w<<5)+lg*4, B at +16
    const int woffA = hoff(lb, (w << 5) + (lg << 2));
    const int woffB = hoff(lb, (w << 5) + 16 + (lg << 2));
    // read offsets: frag kk at j0 = kk*32 + lg*8
    const int roff0 = hoff(lb, 0 * 32 + (lg << 3));
    const int roff1 = hoff(lb, 1 * 32 + (lg << 3));
    const int roff2 = hoff(lb, 2 * 32 + (lg << 3));
    const int roff3 = hoff(lb, 3 * 32 + (lg << 3));

    #pragma unroll 2
    for (int t = 0; t < SEQ - 1; ++t) {
        const int nb = (t + 1) & 1;           // compile-time under unroll-2
        char* hb = hbuf + nb * 4096;

        // ---- hh: 4 independent depth-2 chains (critical path) ----
        f32x4 zz = {0.0f, 0.0f, 0.0f, 0.0f};
        f32x4 zA1, zA2, zB1, zB2;
        zA1 = __builtin_amdgcn_mfma_f32_16x16x32_f16(AhhA[0], hf0, accA, 0, 0, 0);
        zB1 = __builtin_amdgcn_mfma_f32_16x16x32_f16(AhhB[0], hf0, accB, 0, 0, 0);
        zA2 = __builtin_amdgcn_mfma_f32_16x16x32_f16(AhhA[2], hf2, zz,   0, 0, 0);
        zB2 = __builtin_amdgcn_mfma_f32_16x16x32_f16(AhhB[2], hf2, zz,   0, 0, 0);
        zA1 = __builtin_amdgcn_mfma_f32_16x16x32_f16(AhhA[1], hf1, zA1,  0, 0, 0);
        zB1 = __builtin_amdgcn_mfma_f32_16x16x32_f16(AhhB[1], hf1, zB1,  0, 0, 0);
        zA2 = __builtin_amdgcn_mfma_f32_16x16x32_f16(AhhA[3], hf3, zA2,  0, 0, 0);
        zB2 = __builtin_amdgcn_mfma_f32_16x16x32_f16(AhhB[3], hf3, zB2,  0, 0, 0);

        // ---- x ring: refill (for t+4), consume xr1 (for t+1) later ----
        XSlot xnew;
        XLOAD(xnew, xload);
        if (t + 5 < SEQ) xload += XSTEP;

        // ---- h_{t+1} = tanh(z) -> fp16 -> LDS (8B store per subtile) ----
        f32x4 rA, rB;
        #pragma unroll
        for (int r = 0; r < 4; ++r) rA[r] = fast_tanh(zA1[r] + zA2[r]);
        #pragma unroll
        for (int r = 0; r < 4; ++r) rB[r] = fast_tanh(zB1[r] + zB2[r]);
        *(half4v*)(hb + woffA) = pack4(rA);
        *(half4v*)(hb + woffB) = pack4(rB);

        // ---- ih projection for t+1 (off critical path) ----
        {
            half8 xf0 = cvt8(xr1.v0, xr1.v1);
            half8 xf1 = cvt8(xr1.v2, xr1.v3);
            accA = __builtin_amdgcn_mfma_f32_16x16x32_f16(AihA[0], xf0, biasA, 0, 0, 0);
            accA = __builtin_amdgcn_mfma_f32_16x16x32_f16(AihA[1], xf1, accA,  0, 0, 0);
            accB = __builtin_amdgcn_mfma_f32_16x16x32_f16(AihB[0], xf0, biasB, 0, 0, 0);
            accB = __builtin_amdgcn_mfma_f32_16x16x32_f16(AihB[1], xf1, accB,  0, 0, 0);
        }
        xr1 = xr2; xr2 = xr3; xr3 = xnew;

        // ---- publish h_{t+1}, then pull all 128 j as B-frags ----
        asm volatile("s_waitcnt lgkmcnt(0)" ::: "memory");
        __builtin_amdgcn_s_barrier();
        asm volatile("" ::: "memory");

        hf0 = *(const half8*)(hb + roff0);
        hf1 = *(const half8*)(hb + roff1);
        hf2 = *(const half8*)(hb + roff2);
        hf3 = *(const half8*)(hb + roff3);
    }

    // ---- epilogue: t = SEQ-1, h_final -> out (f32) ----
    {
        f32x4 zz = {0.0f, 0.0f, 0.0f, 0.0f};
        f32x4 zA1, zA2, zB1, zB2;
        zA1 = __builtin_amdgcn_mfma_f32_16x16x32_f16(AhhA[0], hf0, accA, 0, 0, 0);
        zB1 = __builtin_amdgcn_mfma_f32_16x16x32_f16(AhhB[0], hf0, accB, 0, 0, 0);
        zA2 = __builtin_amdgcn_mfma_f32_16x16x32_f16(AhhA[2], hf2, zz,   0, 0, 0);
        zB2 = __builtin_amdgcn_mfma_f32_16x16x32_f16(AhhB[2], hf2, zz,   0, 0, 0);
        zA1 = __builtin_amdgcn_mfma_f32_16x16x32_f16(AhhA[1], hf1, zA1,  0, 0, 0);
        zB1 = __builtin_amdgcn_mfma_f32_16x16x32_f16(AhhB[1], hf1, zB1,  0, 0, 0);
        zA2 = __builtin_amdgcn_mfma_f32_16x16x32_f16(AhhA[3], hf3, zA2,  0, 0, 0);
        zB2 = __builtin_amdgcn_mfma_f32_16x16x32_f16(AhhB[3], hf3, zB2,  0, 0, 0);

        f32x4 rA, rB;
        #pragma unroll
        for (int r = 0; r < 4; ++r) rA[r] = fast_tanh(zA1[r] + zA2[r]);
        #pragma unroll
        for (int r = 0; r < 4; ++r) rB[r] = fast_tanh(zB1[r] + zB2[r]);
        float* o = out + (size_t)(bbase + lb) * DH + (w << 5) + (lg << 2);
        *(f32x4*)(o)      = rA;
        *(f32x4*)(o + 16) = rB;
    }
}

extern "C" void kernel_launch(void* const* d_in, const int* in_sizes, int n_in,
                              void* d_out, int out_size, void* d_ws, size_t ws_size,
                              hipStream_t stream) {
    const float* x   = (const float*)d_in[0];
    const float* Wih = (const float*)d_in[1];
    const float* bih = (const float*)d_in[2];
    const float* Whh = (const float*)d_in[3];
    const float* bhh = (const float*)d_in[4];
    float* out = (float*)d_out;
    rnn_fused_scan<<<16, 256, 0, stream>>>(x, Wih, bih, Whh, bhh, out);
}

// Round 5
// 1424.387 us; speedup vs baseline: 2.2013x; 2.2013x over previous
//
#include <hip/hip_runtime.h>

// R5: two-kernel scheme.
//  (1) rnn_prepass: xp[t][b][j] = fp16(W_ih x[t][b] + b_ih + b_hh)  — full-GPU
//      MFMA GEMM, memory-bound (~536 MB traffic), 16384 blocks.
//  (2) rnn_scan_xp: the serial scan, R2's 8-wave structure (2 waves/SIMD for
//      latency hiding — R3b proved 1 wave/SIMD loses 77%) with ALL x work
//      removed: per wave/step = 4 ds_read_b128 (h) + 4 hh MFMA (2 indep
//      chains, C-in = xp[t]) + 4 tanh + 1 ds_write_b64 + 1 prefetched 8B
//      global xp load (depth-3 ring).
//  Falls back to the proven R2 fused kernel if ws_size < 256 MB.

#define SEQ   4096
#define BATCH 256
#define DIN   64
#define DH    128
#define XSTEP (BATCH * DIN)

typedef _Float16 half8  __attribute__((ext_vector_type(8)));
typedef _Float16 half4v __attribute__((ext_vector_type(4)));
typedef _Float16 half2v __attribute__((ext_vector_type(2)));
typedef __fp16   fp16x2 __attribute__((ext_vector_type(2)));
typedef float    f32x4  __attribute__((ext_vector_type(4)));
typedef float    f32x2  __attribute__((ext_vector_type(2)));

union H2 { fp16x2 q; half2v h; unsigned int u; };

// tanh(x) = 1 - 2/(1 + e^{2x}); overflow-free for all finite x.
__device__ __forceinline__ float fast_tanh(float v) {
    float e = __builtin_amdgcn_exp2f(v * 2.88539008177792681472f);
    return 1.0f - 2.0f * __builtin_amdgcn_rcpf(e + 1.0f);
}

__device__ __forceinline__ half2v pk(float a, float b) {
    H2 u; u.q = __builtin_amdgcn_cvt_pkrtz(a, b);
    return u.h;
}

__device__ __forceinline__ half8 cvt8(f32x4 a, f32x4 b) {
    half2v p0 = pk(a[0], a[1]);
    half2v p1 = pk(a[2], a[3]);
    half2v p2 = pk(b[0], b[1]);
    half2v p3 = pk(b[2], b[3]);
    half8 r;
    r[0] = p0[0]; r[1] = p0[1]; r[2] = p1[0]; r[3] = p1[1];
    r[4] = p2[0]; r[5] = p2[1]; r[6] = p3[0]; r[7] = p3[1];
    return r;
}

__device__ __forceinline__ half4v pack4(f32x4 a) {
    half2v q0 = pk(a[0], a[1]);
    half2v q1 = pk(a[2], a[3]);
    half4v r;
    r[0] = q0[0]; r[1] = q0[1]; r[2] = q1[0]; r[3] = q1[1];
    return r;
}

__device__ __forceinline__ f32x4 cvt4f(half4v v) {
    f32x4 r;
    r[0] = (float)v[0]; r[1] = (float)v[1];
    r[2] = (float)v[2]; r[3] = (float)v[3];
    return r;
}

// byte offset of h[b][j] (f16) in a [16][128] tile; 16B-chunk XOR swizzle by b.
__device__ __forceinline__ int hoff(int b, int j) {
    return b * 256 + ((((j >> 3) ^ b) & 15) << 4) + (j & 7) * 2;
}

// ---------------------------------------------------------------------------
// Kernel 1: prepass GEMM.  xp[row][j] = fp16( sum_k Wih[j][k] x[row][k] + bih[j] + bhh[j] )
// row = t*BATCH + b (1,048,576 rows).  Block = 4 waves x 16 rows; wave does
// 16 rows x 128 j = 16 MFMA (8 j-subtiles x K64).
// D[m=j][n=row]: A = Wih (m=j rows), B = x (n=row cols).
// ---------------------------------------------------------------------------
__launch_bounds__(256, 1)
__global__ void rnn_prepass(const float* __restrict__ x,     // [SEQ*BATCH][DIN]
                            const float* __restrict__ Wih,   // [DH][DIN]
                            const float* __restrict__ bih,   // [DH]
                            const float* __restrict__ bhh,   // [DH]
                            _Float16* __restrict__ xp)       // [SEQ*BATCH][DH]
{
    const int tid  = threadIdx.x;
    const int w    = tid >> 6;
    const int lane = tid & 63;
    const int lb   = lane & 15;
    const int lg   = lane >> 4;
    const int rowbase = blockIdx.x * 64 + w * 16;

    // A-frags: Wih for 8 j-subtiles x 2 k-halves
    half8 A[8][2];
    #pragma unroll
    for (int s = 0; s < 8; ++s) {
        #pragma unroll
        for (int kt = 0; kt < 2; ++kt) {
            const float* wr = Wih + (s * 16 + lb) * DIN + kt * 32 + lg * 8;
            half8 f;
            #pragma unroll
            for (int i = 0; i < 8; ++i) f[i] = (_Float16)wr[i];
            A[s][kt] = f;
        }
    }
    f32x4 bias[8];
    #pragma unroll
    for (int s = 0; s < 8; ++s)
        #pragma unroll
        for (int r = 0; r < 4; ++r) {
            int j = s * 16 + lg * 4 + r;
            bias[s][r] = bih[j] + bhh[j];
        }

    // B-frags: x row (rowbase+lb), k = kt*32 + lg*8 .. +7
    const float* xr = x + (size_t)(rowbase + lb) * DIN + lg * 8;
    half8 xf0 = cvt8(*(const f32x4*)(xr),      *(const f32x4*)(xr + 4));
    half8 xf1 = cvt8(*(const f32x4*)(xr + 32), *(const f32x4*)(xr + 36));

    _Float16* op = xp + (size_t)(rowbase + lb) * DH + lg * 4;
    #pragma unroll
    for (int s = 0; s < 8; ++s) {
        f32x4 acc;
        acc = __builtin_amdgcn_mfma_f32_16x16x32_f16(A[s][0], xf0, bias[s], 0, 0, 0);
        acc = __builtin_amdgcn_mfma_f32_16x16x32_f16(A[s][1], xf1, acc,     0, 0, 0);
        *(half4v*)(op + s * 16) = pack4(acc);
    }
}

// ---------------------------------------------------------------------------
// Kernel 2: the scan.  16 blocks x 512 threads (8 waves, j-tile 16 each).
// ---------------------------------------------------------------------------
__launch_bounds__(512, 1)
__global__ void rnn_scan_xp(const _Float16* __restrict__ xp,  // [SEQ][BATCH][DH]
                            const float* __restrict__ Whh,    // [DH][DH]
                            float* __restrict__ out)          // [BATCH][DH]
{
    __shared__ __align__(16) char hbuf[8192];   // 2 x swizzled [16][128] f16

    const int tid   = threadIdx.x;
    const int wave  = tid >> 6;
    const int lane  = tid & 63;
    const int lb    = lane & 15;
    const int lg    = lane >> 4;
    const int bbase = blockIdx.x << 4;
    const int jbase = wave << 4;

    // persistent W_hh A-frags (K=128 -> 4)
    half8 Ahh[4];
    #pragma unroll
    for (int kt = 0; kt < 4; ++kt) {
        const float* wr = Whh + (jbase + lb) * DH + kt * 32 + lg * 8;
        half8 f;
        #pragma unroll
        for (int i = 0; i < 8; ++i) f[i] = (_Float16)wr[i];
        Ahh[kt] = f;
    }

    // xp ring: per lane 4 f16 = xp[t][bbase+lb][jbase + lg*4 .. +3]
    const _Float16* xpp = xp + (size_t)(bbase + lb) * DH + jbase + (lg << 2);
    const size_t XPS = (size_t)BATCH * DH;

    half4v xq1, xq2, xq3;
    f32x4 ci;   // f32 xp[t], C-in of chain 1
    {
        half4v x0 = *(const half4v*)(xpp);
        xq1 = *(const half4v*)(xpp + 1 * XPS);
        xq2 = *(const half4v*)(xpp + 2 * XPS);
        xq3 = *(const half4v*)(xpp + 3 * XPS);
        ci = cvt4f(x0);
    }
    const _Float16* xload = xpp + 4 * XPS;   // -> xp[min(t+4, SEQ-1)]

    half8 hf0, hf1, hf2, hf3;
    {
        half8 z;
        #pragma unroll
        for (int i = 0; i < 8; ++i) z[i] = (_Float16)0.0f;
        hf0 = hf1 = hf2 = hf3 = z;   // h_0 = 0
    }

    const int woff  = hoff(lb, jbase + (lg << 2));
    const int roff0 = hoff(lb, 0 * 32 + (lg << 3));
    const int roff1 = hoff(lb, 1 * 32 + (lg << 3));
    const int roff2 = hoff(lb, 2 * 32 + (lg << 3));
    const int roff3 = hoff(lb, 3 * 32 + (lg << 3));

    #pragma unroll 2
    for (int t = 0; t < SEQ - 1; ++t) {
        const int nb = (t + 1) & 1;
        char* hb = hbuf + nb * 4096;

        // hh: 2 independent depth-2 chains; chain1 C-in = xp[t] (+bias folded in)
        f32x4 zz = {0.0f, 0.0f, 0.0f, 0.0f};
        f32x4 acc1, acc2;
        acc1 = __builtin_amdgcn_mfma_f32_16x16x32_f16(Ahh[0], hf0, ci,   0, 0, 0);
        acc2 = __builtin_amdgcn_mfma_f32_16x16x32_f16(Ahh[2], hf2, zz,   0, 0, 0);
        acc1 = __builtin_amdgcn_mfma_f32_16x16x32_f16(Ahh[1], hf1, acc1, 0, 0, 0);
        acc2 = __builtin_amdgcn_mfma_f32_16x16x32_f16(Ahh[3], hf3, acc2, 0, 0, 0);

        // prefetch xp[t+4] (clamped at tail; extra loads of last row unused)
        half4v xnew = *(const half4v*)xload;
        if (t + 5 < SEQ) xload += XPS;

        // h_{t+1} = tanh(z) -> fp16 -> LDS
        f32x4 rA;
        #pragma unroll
        for (int r = 0; r < 4; ++r) rA[r] = fast_tanh(acc1[r] + acc2[r]);
        *(half4v*)(hb + woff) = pack4(rA);

        // rotate ring; ci <- xp[t+1] (off critical path)
        ci = cvt4f(xq1);
        xq1 = xq2; xq2 = xq3; xq3 = xnew;

        // publish h_{t+1}; manual lgkm-only drain (no vmcnt -> xp loads stay in flight)
        asm volatile("s_waitcnt lgkmcnt(0)" ::: "memory");
        __builtin_amdgcn_s_barrier();
        asm volatile("" ::: "memory");

        hf0 = *(const half8*)(hb + roff0);
        hf2 = *(const half8*)(hb + roff2);
        hf1 = *(const half8*)(hb + roff1);
        hf3 = *(const half8*)(hb + roff3);
    }

    // epilogue: t = SEQ-1 -> h_final -> out (f32)
    {
        f32x4 zz = {0.0f, 0.0f, 0.0f, 0.0f};
        f32x4 acc1, acc2;
        acc1 = __builtin_amdgcn_mfma_f32_16x16x32_f16(Ahh[0], hf0, ci,   0, 0, 0);
        acc2 = __builtin_amdgcn_mfma_f32_16x16x32_f16(Ahh[2], hf2, zz,   0, 0, 0);
        acc1 = __builtin_amdgcn_mfma_f32_16x16x32_f16(Ahh[1], hf1, acc1, 0, 0, 0);
        acc2 = __builtin_amdgcn_mfma_f32_16x16x32_f16(Ahh[3], hf3, acc2, 0, 0, 0);
        f32x4 rA;
        #pragma unroll
        for (int r = 0; r < 4; ++r) rA[r] = fast_tanh(acc1[r] + acc2[r]);
        *(f32x4*)(out + (size_t)(bbase + lb) * DH + jbase + (lg << 2)) = rA;
    }
}

// ---------------------------------------------------------------------------
// Fallback (R2, proven 1768 us): used only if ws_size < SEQ*BATCH*DH*2 bytes.
// ---------------------------------------------------------------------------
__device__ __forceinline__ int hoffc(int b, int chunk, int lo) {
    return b * 256 + ((chunk ^ b) << 4) + lo;
}
__device__ __forceinline__ int xoff_lds(int b, int chunk, int lo) {
    return b * 128 + (((chunk ^ (b & 7)) << 4) + lo);
}

__launch_bounds__(512, 1)
__global__ void rnn_fused_scan_r2(const float* __restrict__ x,
                                  const float* __restrict__ Wih,
                                  const float* __restrict__ bih,
                                  const float* __restrict__ Whh,
                                  const float* __restrict__ bhh,
                                  float* __restrict__ out)
{
    __shared__ __align__(16) char lds[12288];
    char* hbuf = lds;
    char* xbuf = lds + 8192;

    const int tid   = threadIdx.x;
    const int wave  = tid >> 6;
    const int lane  = tid & 63;
    const int lb    = lane & 15;
    const int lg    = lane >> 4;
    const int bbase = blockIdx.x << 4;
    const int jbase = wave << 4;

    half8 Ahh[4], Aih[2];
    #pragma unroll
    for (int kt = 0; kt < 4; ++kt) {
        const float* wr = Whh + (jbase + lb) * DH + kt * 32 + lg * 8;
        half8 f;
        #pragma unroll
        for (int i = 0; i < 8; ++i) f[i] = (_Float16)wr[i];
        Ahh[kt] = f;
    }
    #pragma unroll
    for (int kt = 0; kt < 2; ++kt) {
        const float* wr = Wih + (jbase + lb) * DIN + kt * 32 + lg * 8;
        half8 f;
        #pragma unroll
        for (int i = 0; i < 8; ++i) f[i] = (_Float16)wr[i];
        Aih[kt] = f;
    }
    f32x4 bias;
    #pragma unroll
    for (int r = 0; r < 4; ++r) {
        int j = jbase + lg * 4 + r;
        bias[r] = bih[j] + bhh[j];
    }

    const int bx = tid >> 5;
    const int kx = (tid & 31) << 1;
    const float* xlane = x + (size_t)(bbase + bx) * DIN + kx;

    f32x2 r0  = *(const f32x2*)(xlane + 0 * (size_t)XSTEP);
    f32x2 rx0 = *(const f32x2*)(xlane + 1 * (size_t)XSTEP);
    f32x2 rx1 = *(const f32x2*)(xlane + 2 * (size_t)XSTEP);
    f32x2 rx2 = *(const f32x2*)(xlane + 3 * (size_t)XSTEP);
    {
        half2v p; p[0] = (_Float16)r0[0]; p[1] = (_Float16)r0[1];
        *(half2v*)(xbuf + xoff_lds(bx, kx >> 3, (kx & 7) * 2)) = p;
    }
    const float* xload = xlane + 4 * (size_t)XSTEP;

    half8 hf0, hf1, hf2, hf3, xf0, xf1;
    {
        half8 z;
        #pragma unroll
        for (int i = 0; i < 8; ++i) z[i] = (_Float16)0.0f;
        hf0 = hf1 = hf2 = hf3 = z;
    }

    asm volatile("s_waitcnt lgkmcnt(0)" ::: "memory");
    __builtin_amdgcn_s_barrier();
    asm volatile("" ::: "memory");
    xf0 = *(const half8*)(xbuf + xoff_lds(lb, 0 * 4 + lg, 0));
    xf1 = *(const half8*)(xbuf + xoff_lds(lb, 1 * 4 + lg, 0));

    f32x4 acc_ih;
    acc_ih = __builtin_amdgcn_mfma_f32_16x16x32_f16(Aih[0], xf0, bias,   0, 0, 0);
    acc_ih = __builtin_amdgcn_mfma_f32_16x16x32_f16(Aih[1], xf1, acc_ih, 0, 0, 0);

    #pragma unroll 2
    for (int t = 0; t < SEQ - 1; ++t) {
        f32x4 zz = {0.0f, 0.0f, 0.0f, 0.0f};
        f32x4 acc1, acc2;
        acc1 = __builtin_amdgcn_mfma_f32_16x16x32_f16(Ahh[0], hf0, acc_ih, 0, 0, 0);
        acc2 = __builtin_amdgcn_mfma_f32_16x16x32_f16(Ahh[2], hf2, zz,     0, 0, 0);
        acc1 = __builtin_amdgcn_mfma_f32_16x16x32_f16(Ahh[1], hf1, acc1,   0, 0, 0);
        acc2 = __builtin_amdgcn_mfma_f32_16x16x32_f16(Ahh[3], hf3, acc2,   0, 0, 0);

        const int nb = (t + 1) & 1;
        {
            half2v p; p[0] = (_Float16)rx0[0]; p[1] = (_Float16)rx0[1];
            *(half2v*)(xbuf + nb * 2048 + xoff_lds(bx, kx >> 3, (kx & 7) * 2)) = p;
        }
        rx0 = rx1; rx1 = rx2;
        rx2 = *(const f32x2*)xload;
        if (t + 5 < SEQ) xload += XSTEP;

        f32x4 hv;
        #pragma unroll
        for (int r = 0; r < 4; ++r) hv[r] = fast_tanh(acc1[r] + acc2[r]);
        {
            half4v p;
            #pragma unroll
            for (int r = 0; r < 4; ++r) p[r] = (_Float16)hv[r];
            *(half4v*)(hbuf + nb * 4096 + hoffc(lb, (wave << 1) + (lg >> 1), (lg & 1) * 8)) = p;
        }

        asm volatile("s_waitcnt lgkmcnt(0)" ::: "memory");
        __builtin_amdgcn_s_barrier();
        asm volatile("" ::: "memory");

        hf0 = *(const half8*)(hbuf + nb * 4096 + hoffc(lb, 0 * 4 + lg, 0));
        hf2 = *(const half8*)(hbuf + nb * 4096 + hoffc(lb, 2 * 4 + lg, 0));
        hf1 = *(const half8*)(hbuf + nb * 4096 + hoffc(lb, 1 * 4 + lg, 0));
        hf3 = *(const half8*)(hbuf + nb * 4096 + hoffc(lb, 3 * 4 + lg, 0));
        xf0 = *(const half8*)(xbuf + nb * 2048 + xoff_lds(lb, 0 * 4 + lg, 0));
        xf1 = *(const half8*)(xbuf + nb * 2048 + xoff_lds(lb, 1 * 4 + lg, 0));

        acc_ih = __builtin_amdgcn_mfma_f32_16x16x32_f16(Aih[0], xf0, bias,   0, 0, 0);
        acc_ih = __builtin_amdgcn_mfma_f32_16x16x32_f16(Aih[1], xf1, acc_ih, 0, 0, 0);
    }

    {
        f32x4 zz = {0.0f, 0.0f, 0.0f, 0.0f};
        f32x4 acc1, acc2;
        acc1 = __builtin_amdgcn_mfma_f32_16x16x32_f16(Ahh[0], hf0, acc_ih, 0, 0, 0);
        acc2 = __builtin_amdgcn_mfma_f32_16x16x32_f16(Ahh[2], hf2, zz,     0, 0, 0);
        acc1 = __builtin_amdgcn_mfma_f32_16x16x32_f16(Ahh[1], hf1, acc1,   0, 0, 0);
        acc2 = __builtin_amdgcn_mfma_f32_16x16x32_f16(Ahh[3], hf3, acc2,   0, 0, 0);
        f32x4 res;
        #pragma unroll
        for (int r = 0; r < 4; ++r) res[r] = fast_tanh(acc1[r] + acc2[r]);
        *(f32x4*)(out + (size_t)(bbase + lb) * DH + jbase + (lg << 2)) = res;
    }
}

extern "C" void kernel_launch(void* const* d_in, const int* in_sizes, int n_in,
                              void* d_out, int out_size, void* d_ws, size_t ws_size,
                              hipStream_t stream) {
    const float* x   = (const float*)d_in[0];
    const float* Wih = (const float*)d_in[1];
    const float* bih = (const float*)d_in[2];
    const float* Whh = (const float*)d_in[3];
    const float* bhh = (const float*)d_in[4];
    float* out = (float*)d_out;

    const size_t need = (size_t)SEQ * BATCH * DH * sizeof(_Float16);  // 256 MB
    if (ws_size >= need) {
        _Float16* xp = (_Float16*)d_ws;
        rnn_prepass<<<SEQ * BATCH / 64, 256, 0, stream>>>(x, Wih, bih, bhh, xp);
        rnn_scan_xp<<<16, 512, 0, stream>>>(xp, Whh, out);
    } else {
        rnn_fused_scan_r2<<<16, 512, 0, stream>>>(x, Wih, bih, Whh, bhh, out);
    }
}